// Round 1
// baseline (259960.864 us; speedup 1.0000x reference)
//
#include <hip/hip_runtime.h>
#include <math.h>

#define HDIM 128
#define SORB_N 64

__device__ __forceinline__ float rcp_fast(float x) { return __builtin_amdgcn_rcpf(x); }

__device__ __forceinline__ float sigmoid_f(float x) {
    float e = __expf(-x);
    return rcp_fast(1.0f + e);
}

__device__ __forceinline__ float tanh_f(float x) {
    float ax = fabsf(x);
    float e  = __expf(-2.0f * ax);
    float t  = (1.0f - e) * rcp_fast(1.0f + e);
    return x >= 0.0f ? t : -t;
}

// dot of 32 consecutive weight floats (16B aligned) with 32 register h values
__device__ __forceinline__ float dot32(const float* __restrict__ w, const float* h) {
    const float4* wv = (const float4*)w;
    float s = 0.0f;
#pragma unroll
    for (int kk = 0; kk < 8; ++kk) {
        float4 a = wv[kk];
        s = fmaf(a.x, h[4 * kk + 0], s);
        s = fmaf(a.y, h[4 * kk + 1], s);
        s = fmaf(a.z, h[4 * kk + 2], s);
        s = fmaf(a.w, h[4 * kk + 3], s);
    }
    return s;
}

// sum across the 4-lane quad (lanes 4e..4e+3); result valid in all 4 lanes
__device__ __forceinline__ float qsum(float s) {
    s += __shfl_xor(s, 1);
    s += __shfl_xor(s, 2);
    return s;
}

__global__ void __launch_bounds__(256, 2) rnn_wf_kernel(
    const int*   __restrict__ x,
    const float* __restrict__ w_ih0,
    const float* __restrict__ w_hh0,
    const float* __restrict__ w_ih1,
    const float* __restrict__ w_hh1,
    const float* __restrict__ w_lin,
    const float* __restrict__ b_lin,
    float*       __restrict__ out,
    int nbatch)
{
    // transposed h mirrors: [j][e] so the h_prev[j] read is conflict-free
    __shared__ float lds_h0[HDIM * 64];
    __shared__ float lds_h1[HDIM * 64];

    const int t  = threadIdx.x;
    const int q  = t & 3;       // k-chunk 0..3 (owns h[32q .. 32q+31])
    const int eL = t >> 2;      // local element 0..63
    const int e  = blockIdx.x * 64 + eL;
    if (e >= nbatch) return;

    // ---- pack this element's 64 bits into a mask (quad-cooperative) ----
    unsigned long long bmask = 0ull;
    {
        const int* xr = x + (size_t)e * SORB_N + q * 16;
#pragma unroll
        for (int i = 0; i < 16; ++i) {
            unsigned long long b = (unsigned long long)((xr[i] + 1) >> 1);
            bmask |= b << (q * 16 + i);
        }
        bmask |= __shfl_xor(bmask, 1);
        bmask |= __shfl_xor(bmask, 2);
    }

    float h0r[32], h1r[32];
#pragma unroll
    for (int i = 0; i < 32; ++i) { h0r[i] = 0.0f; h1r[i] = 0.0f; }
#pragma unroll
    for (int i = 0; i < 32; ++i) {
        lds_h0[(q * 32 + i) * 64 + eL] = 0.0f;
        lds_h1[(q * 32 + i) * 64 + eL] = 0.0f;
    }

    const float* wq_hh0 = w_hh0 + q * 32;
    const float* wq_ih1 = w_ih1 + q * 32;
    const float* wq_hh1 = w_hh1 + q * 32;
    const float2* wih0v = (const float2*)w_ih0;
    const float bl0 = b_lin[0];
    const float bl1 = b_lin[1];

    float amp = 1.0f, phase = 0.0f, num_up = 0.0f, num_down = 0.0f;
    int prev = -1;  // previous bit; -1 => x0 = zeros (step 0)

    for (int step = 0; step < SORB_N; ++step) {
        const int bit = (int)((bmask >> step) & 1ull);

        // ---------------- layer 0: h0 = GRU(onehot(prev), h0) ----------------
        for (int j = 0; j < HDIM; ++j) {
            float sr = dot32(wq_hh0 + (size_t)j * HDIM,              h0r);
            float sz = dot32(wq_hh0 + (size_t)(HDIM + j) * HDIM,     h0r);
            float sn = dot32(wq_hh0 + (size_t)(2 * HDIM + j) * HDIM, h0r);
            sr = qsum(sr); sz = qsum(sz); sn = qsum(sn);

            float gir = 0.0f, giz = 0.0f, gin = 0.0f;
            if (prev >= 0) {  // uniform branch (false only at step 0)
                float2 a = wih0v[j];
                float2 b = wih0v[HDIM + j];
                float2 c = wih0v[2 * HDIM + j];
                gir = prev ? a.y : a.x;
                giz = prev ? b.y : b.x;
                gin = prev ? c.y : c.x;
            }
            float r  = sigmoid_f(gir + sr);
            float zg = sigmoid_f(giz + sz);
            float n  = tanh_f(gin + r * sn);
            float hp = lds_h0[j * 64 + eL];
            float hn = (1.0f - zg) * n + zg * hp;
            if (q == 0) lds_h0[j * 64 + eL] = hn;
        }
#pragma unroll
        for (int i = 0; i < 32; ++i) h0r[i] = lds_h0[(q * 32 + i) * 64 + eL];

        // ---------------- layer 1: h1 = GRU(h0, h1) ----------------
        for (int j = 0; j < HDIM; ++j) {
            float s_ir = dot32(wq_ih1 + (size_t)j * HDIM,              h0r);
            float s_iz = dot32(wq_ih1 + (size_t)(HDIM + j) * HDIM,     h0r);
            float s_in = dot32(wq_ih1 + (size_t)(2 * HDIM + j) * HDIM, h0r);
            float s_hr = dot32(wq_hh1 + (size_t)j * HDIM,              h1r);
            float s_hz = dot32(wq_hh1 + (size_t)(HDIM + j) * HDIM,     h1r);
            float s_hn = dot32(wq_hh1 + (size_t)(2 * HDIM + j) * HDIM, h1r);

            float gr = qsum(s_ir + s_hr);
            float gz = qsum(s_iz + s_hz);
            float gin = qsum(s_in);
            float ghn = qsum(s_hn);

            float r  = sigmoid_f(gr);
            float zg = sigmoid_f(gz);
            float n  = tanh_f(gin + r * ghn);
            float hp = lds_h1[j * 64 + eL];
            float hn = (1.0f - zg) * n + zg * hp;
            if (q == 0) lds_h1[j * 64 + eL] = hn;
        }
#pragma unroll
        for (int i = 0; i < 32; ++i) h1r[i] = lds_h1[(q * 32 + i) * 64 + eL];

        // ---------------- head: logits, softmax-sqrt, mask, amp/phase --------
        float l0 = qsum(dot32(w_lin + q * 32,        h1r)) + bl0;
        float l1 = qsum(dot32(w_lin + HDIM + q * 32, h1r)) + bl1;

        // softmax via complementary sigmoids (relatively accurate for both)
        float p0 = sigmoid_f(l0 - l1);
        float p1 = sigmoid_f(l1 - l0);
        float y0 = sqrtf(p0), y1 = sqrtf(p1);
        float ph0 = 3.14159265358979323846f * l0 * rcp_fast(1.0f + fabsf(l0));
        float ph1 = 3.14159265358979323846f * l1 * rcp_fast(1.0f + fabsf(l1));

        const bool is_even = (step & 1) == 0;
        float num   = is_even ? num_up : num_down;
        float lower = -16.0f + (float)(step >> 1);   // baseline = 16 - 32
        float occ   = (num < 16.0f) ? 1.0f : 0.0f;   // alpha = 16
        float unocc = (num > lower) ? 1.0f : 0.0f;
        if (step >= 16) {                             // NELE//2
            float m0 = y0 * unocc, m1 = y1 * occ;
            float nrm = fmaxf(sqrtf(m0 * m0 + m1 * m1), 1e-12f);
            float rn  = rcp_fast(nrm);
            y0 = m0 * rn; y1 = m1 * rn;
        }
        if (is_even) num_up += (float)bit; else num_down += (float)bit;

        amp   *= bit ? y1 : y0;
        phase += bit ? ph1 : ph0;
        prev   = bit;
    }

    if (q == 0) {
        float s, c;
        sincosf(phase, &s, &c);
        out[e]          = amp * c;
        out[nbatch + e] = amp * s;
    }
}

extern "C" void kernel_launch(void* const* d_in, const int* in_sizes, int n_in,
                              void* d_out, int out_size, void* d_ws, size_t ws_size,
                              hipStream_t stream) {
    const int*   x     = (const int*)  d_in[0];
    const float* w_ih0 = (const float*)d_in[1];
    const float* w_hh0 = (const float*)d_in[2];
    const float* w_ih1 = (const float*)d_in[3];
    const float* w_hh1 = (const float*)d_in[4];
    const float* w_lin = (const float*)d_in[5];
    const float* b_lin = (const float*)d_in[6];
    float* out = (float*)d_out;

    const int nbatch = in_sizes[0] / SORB_N;
    const int blocks = (nbatch + 63) / 64;
    rnn_wf_kernel<<<blocks, 256, 0, stream>>>(x, w_ih0, w_hh0, w_ih1, w_hh1,
                                              w_lin, b_lin, out, nbatch);
}

// Round 3
// 16175.002 us; speedup vs baseline: 16.0718x; 16.0718x over previous
//
#include <hip/hip_runtime.h>
#include <math.h>

#define NSTEP 64
#define PI_F 3.14159265358979323846f

typedef _Float16 half8 __attribute__((ext_vector_type(8)));
typedef float f32x4 __attribute__((ext_vector_type(4)));
typedef int int4v __attribute__((ext_vector_type(4)));

#define MFMA(a, b, c) __builtin_amdgcn_mfma_f32_16x16x32_f16(a, b, c, 0, 0, 0)

// ws layout in halfs: [whh0_hi 49152][whh0_lo 49152][wcat_hi 98304][wcat_lo 98304]
#define OFF_HH0_LO 49152
#define OFF_CAT_HI 98304
#define OFF_CAT_LO 196608

__device__ __forceinline__ float rcp_fast(float x) { return __builtin_amdgcn_rcpf(x); }
__device__ __forceinline__ float sigmoid_f(float x) {
    float e = __expf(-x);
    return rcp_fast(1.0f + e);
}
__device__ __forceinline__ float tanh_f(float x) {
    float ax = fabsf(x);
    float e  = __expf(-2.0f * ax);
    float t  = (1.0f - e) * rcp_fast(1.0f + e);
    return x >= 0.0f ? t : -t;
}
__device__ __forceinline__ float f16lo(int v) {
    return (float)__builtin_bit_cast(_Float16, (unsigned short)(v & 0xffff));
}
__device__ __forceinline__ float f16hi(int v) {
    return (float)__builtin_bit_cast(_Float16, (unsigned short)((unsigned)v >> 16));
}
__device__ __forceinline__ int pack_split(float f) {
    _Float16 hi = (_Float16)f;
    _Float16 lo = (_Float16)(f - (float)hi);
    return (int)__builtin_bit_cast(unsigned short, hi) |
           ((int)__builtin_bit_cast(unsigned short, lo) << 16);
}

// Prep: split fp32 weights into f16 hi/lo planes; concat [w_ih1|w_hh1] along K.
__global__ void prep_kernel(const float* __restrict__ whh0,
                            const float* __restrict__ wih1,
                            const float* __restrict__ whh1,
                            _Float16* __restrict__ wsp) {
    int i = blockIdx.x * 256 + threadIdx.x;
    if (i < 49152) {
        float v = whh0[i];
        _Float16 h = (_Float16)v;
        wsp[i] = h;
        wsp[OFF_HH0_LO + i] = (_Float16)(v - (float)h);
    }
    if (i < 98304) {
        int n = i >> 8, k = i & 255;
        float v = (k < 128) ? wih1[(n << 7) + k] : whh1[(n << 7) + k - 128];
        _Float16 h = (_Float16)v;
        wsp[OFF_CAT_HI + i] = h;
        wsp[OFF_CAT_LO + i] = (_Float16)(v - (float)h);
    }
}

__global__ void __launch_bounds__(256, 2) rnn_wf_mfma(
    const int*   __restrict__ x,
    const float* __restrict__ w_ih0,
    const float* __restrict__ w_lin,
    const float* __restrict__ b_lin,
    const _Float16* __restrict__ wsp,
    float*       __restrict__ out,
    int nbatch)
{
    __shared__ float gi0T[2][3][128];     // [bit][gate][d]
    __shared__ int   hscr[4][32 * 132];   // per-wave packed (hi|lo16) h scratch

    const int lane = threadIdx.x & 63;
    const int wv   = threadIdx.x >> 6;
    const int l4   = lane & 15;
    const int q    = lane >> 4;
    const int eBase = blockIdx.x * 128 + wv * 32;

    // stage gi0T: gi0T[b][g][d] = w_ih0[(g*128+d)*2 + b]
    for (int idx = threadIdx.x; idx < 768; idx += 256) {
        int b = idx / 384, rem = idx - b * 384;
        ((float*)gi0T)[b * 384 + rem] = w_ih0[rem * 2 + b];
    }
    __syncthreads();

    // ---- per-element bit masks (2 elements per lane) ----
    unsigned long long bm[2];
#pragma unroll
    for (int et = 0; et < 2; ++et) {
        int e = eBase + et * 16 + l4;
        if (e >= nbatch) e = nbatch - 1;
        const int* xr = x + (size_t)e * 64 + q * 16;
        unsigned long long m = 0ull;
#pragma unroll
        for (int i = 0; i < 16; ++i)
            m |= ((unsigned long long)((unsigned)(xr[i] + 1) >> 1)) << (q * 16 + i);
        m |= __shfl_xor(m, 16);
        m |= __shfl_xor(m, 32);
        bm[et] = m;
    }

    const _Float16* Whh0_hi = wsp;
    const _Float16* Whh0_lo = wsp + OFF_HH0_LO;
    const _Float16* Wcat_hi = wsp + OFF_CAT_HI;
    const _Float16* Wcat_lo = wsp + OFF_CAT_LO;
    const float bl0 = b_lin[0], bl1 = b_lin[1];

    // h state as B-operand fragments (hi/lo f16), [kchunk][etile]
    // b?h[kc][et][j] = h[e = eBase+16*et+l4][dim = 32*kc + 8*q + j]
    half8 b0h[4][2], b0l[4][2], b1h[4][2], b1l[4][2];
    const half8 hz = {0, 0, 0, 0, 0, 0, 0, 0};
#pragma unroll
    for (int kc = 0; kc < 4; ++kc)
#pragma unroll
        for (int et = 0; et < 2; ++et) {
            b0h[kc][et] = hz; b0l[kc][et] = hz;
            b1h[kc][et] = hz; b1l[kc][et] = hz;
        }

    float amp[2] = {1.0f, 1.0f}, phs[2] = {0.0f, 0.0f};
    float nu[2] = {0.0f, 0.0f}, nd[2] = {0.0f, 0.0f};

    for (int step = 0; step < NSTEP; ++step) {
        __syncthreads();  // phase-lock waves for L1 weight reuse

        // ================= Layer 0: G^T = W_hh0 * h0^T =================
#pragma unroll
        for (int c = 0; c < 8; ++c) {
            f32x4 aR[2], aZ[2], aN[2];
#pragma unroll
            for (int et = 0; et < 2; ++et) {
                aR[et] = (f32x4){0, 0, 0, 0};
                aZ[et] = (f32x4){0, 0, 0, 0};
                aN[et] = (f32x4){0, 0, 0, 0};
            }
#pragma unroll
            for (int kc = 0; kc < 4; ++kc) {
                int off = (16 * c + l4) * 128 + 32 * kc + 8 * q;
                half8 ahR = *(const half8*)(Whh0_hi + off);
                half8 alR = *(const half8*)(Whh0_lo + off);
                half8 ahZ = *(const half8*)(Whh0_hi + off + 128 * 128);
                half8 alZ = *(const half8*)(Whh0_lo + off + 128 * 128);
                half8 ahN = *(const half8*)(Whh0_hi + off + 256 * 128);
                half8 alN = *(const half8*)(Whh0_lo + off + 256 * 128);
#pragma unroll
                for (int et = 0; et < 2; ++et) {
                    half8 bh = b0h[kc][et], bl = b0l[kc][et];
                    aR[et] = MFMA(ahR, bh, aR[et]);
                    aZ[et] = MFMA(ahZ, bh, aZ[et]);
                    aN[et] = MFMA(ahN, bh, aN[et]);
                    aR[et] = MFMA(ahR, bl, aR[et]);
                    aZ[et] = MFMA(ahZ, bl, aZ[et]);
                    aN[et] = MFMA(ahN, bl, aN[et]);
                    aR[et] = MFMA(alR, bh, aR[et]);
                    aZ[et] = MFMA(alZ, bh, aZ[et]);
                    aN[et] = MFMA(alN, bh, aN[et]);
                }
            }
            // ---- epilogue: rows d = 16c + 4q + r, element e = eBase+16et+l4 ----
#pragma unroll
            for (int et = 0; et < 2; ++et) {
                f32x4 giR = {0, 0, 0, 0}, giZ = {0, 0, 0, 0}, giN = {0, 0, 0, 0};
                if (step > 0) {
                    int pb = (int)((bm[et] >> (step - 1)) & 1ull);
                    const float* gp = &gi0T[pb][0][0];
                    int d0 = 16 * c + 4 * q;
                    giR = *(const f32x4*)(gp + d0);
                    giZ = *(const f32x4*)(gp + 128 + d0);
                    giN = *(const f32x4*)(gp + 256 + d0);
                }
                // h0_prev[d][e]: dim d lives in frag kc=c>>1 on lane (q'=2(c&1)+(q>>1), l4=e),
                // register j = 4*(q&1)+r. Shuffle whole frag, select locally.
                int4v Hh = __builtin_bit_cast(int4v, b0h[c >> 1][et]);
                int4v Hl = __builtin_bit_cast(int4v, b0l[c >> 1][et]);
                int src = (((2 * c + (q >> 1)) & 3) << 4) | l4;
                int h0s = __shfl(Hh[0], src), h1s = __shfl(Hh[1], src);
                int h2s = __shfl(Hh[2], src), h3s = __shfl(Hh[3], src);
                int g0s = __shfl(Hl[0], src), g1s = __shfl(Hl[1], src);
                int g2s = __shfl(Hl[2], src), g3s = __shfl(Hl[3], src);
                int qodd = q & 1;
                int ah0 = qodd ? h2s : h0s;
                int ah1 = qodd ? h3s : h1s;
                int al0 = qodd ? g2s : g0s;
                int al1 = qodd ? g3s : g1s;
                float hp[4];
                hp[0] = f16lo(ah0) + f16lo(al0);
                hp[1] = f16hi(ah0) + f16hi(al0);
                hp[2] = f16lo(ah1) + f16lo(al1);
                hp[3] = f16hi(ah1) + f16hi(al1);

                int4v pk;
#pragma unroll
                for (int r = 0; r < 4; ++r) {
                    float rr = sigmoid_f(giR[r] + aR[et][r]);
                    float zz = sigmoid_f(giZ[r] + aZ[et][r]);
                    float nn = tanh_f(giN[r] + rr * aN[et][r]);
                    float hn = (1.0f - zz) * nn + zz * hp[r];
                    pk[r] = pack_split(hn);
                }
                *(int4v*)&hscr[wv][(et * 16 + l4) * 132 + 16 * c + 4 * q] = pk;
            }
        }
        // rebuild h0 B-frags from scratch
#pragma unroll
        for (int kc = 0; kc < 4; ++kc)
#pragma unroll
            for (int et = 0; et < 2; ++et) {
                const int4v* p = (const int4v*)&hscr[wv][(et * 16 + l4) * 132 + 32 * kc + 8 * q];
                int4v p0 = p[0], p1 = p[1];
                int4v hi, lo;
                hi[0] = (p0[0] & 0xffff) | (p0[1] << 16);
                hi[1] = (p0[2] & 0xffff) | (p0[3] << 16);
                hi[2] = (p1[0] & 0xffff) | (p1[1] << 16);
                hi[3] = (p1[2] & 0xffff) | (p1[3] << 16);
                lo[0] = (int)(((unsigned)p0[0]) >> 16) | (p0[1] & 0xffff0000);
                lo[1] = (int)(((unsigned)p0[2]) >> 16) | (p0[3] & 0xffff0000);
                lo[2] = (int)(((unsigned)p1[0]) >> 16) | (p1[1] & 0xffff0000);
                lo[3] = (int)(((unsigned)p1[2]) >> 16) | (p1[3] & 0xffff0000);
                b0h[kc][et] = __builtin_bit_cast(half8, hi);
                b0l[kc][et] = __builtin_bit_cast(half8, lo);
            }

        __syncthreads();

        // ===== Layer 1: G^T = [Wih1|Whh1] * [h0;h1]^T, N-gate split =====
        float l0p[2] = {0.0f, 0.0f}, l1p[2] = {0.0f, 0.0f};
#pragma unroll
        for (int c = 0; c < 8; ++c) {
            f32x4 aR[2], aZ[2], aNi[2], aNh[2];
#pragma unroll
            for (int et = 0; et < 2; ++et) {
                aR[et]  = (f32x4){0, 0, 0, 0};
                aZ[et]  = (f32x4){0, 0, 0, 0};
                aNi[et] = (f32x4){0, 0, 0, 0};
                aNh[et] = (f32x4){0, 0, 0, 0};
            }
#pragma unroll
            for (int kc = 0; kc < 8; ++kc) {
                int off = (16 * c + l4) * 256 + 32 * kc + 8 * q;
                half8 ahR = *(const half8*)(Wcat_hi + off);
                half8 alR = *(const half8*)(Wcat_lo + off);
                half8 ahZ = *(const half8*)(Wcat_hi + off + 128 * 256);
                half8 alZ = *(const half8*)(Wcat_lo + off + 128 * 256);
                half8 ahN = *(const half8*)(Wcat_hi + off + 256 * 256);
                half8 alN = *(const half8*)(Wcat_lo + off + 256 * 256);
#pragma unroll
                for (int et = 0; et < 2; ++et) {
                    half8 bh = (kc < 4) ? b0h[kc][et] : b1h[kc - 4][et];
                    half8 bl = (kc < 4) ? b0l[kc][et] : b1l[kc - 4][et];
                    aR[et] = MFMA(ahR, bh, aR[et]);
                    aZ[et] = MFMA(ahZ, bh, aZ[et]);
                    aR[et] = MFMA(ahR, bl, aR[et]);
                    aZ[et] = MFMA(ahZ, bl, aZ[et]);
                    aR[et] = MFMA(alR, bh, aR[et]);
                    aZ[et] = MFMA(alZ, bh, aZ[et]);
                    if (kc < 4) {
                        aNi[et] = MFMA(ahN, bh, aNi[et]);
                        aNi[et] = MFMA(ahN, bl, aNi[et]);
                        aNi[et] = MFMA(alN, bh, aNi[et]);
                    } else {
                        aNh[et] = MFMA(ahN, bh, aNh[et]);
                        aNh[et] = MFMA(ahN, bl, aNh[et]);
                        aNh[et] = MFMA(alN, bh, aNh[et]);
                    }
                }
            }
#pragma unroll
            for (int et = 0; et < 2; ++et) {
                int4v Hh = __builtin_bit_cast(int4v, b1h[c >> 1][et]);
                int4v Hl = __builtin_bit_cast(int4v, b1l[c >> 1][et]);
                int src = (((2 * c + (q >> 1)) & 3) << 4) | l4;
                int h0s = __shfl(Hh[0], src), h1s = __shfl(Hh[1], src);
                int h2s = __shfl(Hh[2], src), h3s = __shfl(Hh[3], src);
                int g0s = __shfl(Hl[0], src), g1s = __shfl(Hl[1], src);
                int g2s = __shfl(Hl[2], src), g3s = __shfl(Hl[3], src);
                int qodd = q & 1;
                int ah0 = qodd ? h2s : h0s;
                int ah1 = qodd ? h3s : h1s;
                int al0 = qodd ? g2s : g0s;
                int al1 = qodd ? g3s : g1s;
                float hp[4];
                hp[0] = f16lo(ah0) + f16lo(al0);
                hp[1] = f16hi(ah0) + f16hi(al0);
                hp[2] = f16lo(ah1) + f16lo(al1);
                hp[3] = f16hi(ah1) + f16hi(al1);

                f32x4 wl0 = *(const f32x4*)(w_lin + 16 * c + 4 * q);
                f32x4 wl1 = *(const f32x4*)(w_lin + 128 + 16 * c + 4 * q);
                int4v pk;
#pragma unroll
                for (int r = 0; r < 4; ++r) {
                    float rr = sigmoid_f(aR[et][r]);
                    float zz = sigmoid_f(aZ[et][r]);
                    float nn = tanh_f(aNi[et][r] + rr * aNh[et][r]);
                    float hn = (1.0f - zz) * nn + zz * hp[r];
                    l0p[et] = fmaf(hn, wl0[r], l0p[et]);
                    l1p[et] = fmaf(hn, wl1[r], l1p[et]);
                    pk[r] = pack_split(hn);
                }
                *(int4v*)&hscr[wv][(et * 16 + l4) * 132 + 16 * c + 4 * q] = pk;
            }
        }
        // rebuild h1 B-frags
#pragma unroll
        for (int kc = 0; kc < 4; ++kc)
#pragma unroll
            for (int et = 0; et < 2; ++et) {
                const int4v* p = (const int4v*)&hscr[wv][(et * 16 + l4) * 132 + 32 * kc + 8 * q];
                int4v p0 = p[0], p1 = p[1];
                int4v hi, lo;
                hi[0] = (p0[0] & 0xffff) | (p0[1] << 16);
                hi[1] = (p0[2] & 0xffff) | (p0[3] << 16);
                hi[2] = (p1[0] & 0xffff) | (p1[1] << 16);
                hi[3] = (p1[2] & 0xffff) | (p1[3] << 16);
                lo[0] = (int)(((unsigned)p0[0]) >> 16) | (p0[1] & 0xffff0000);
                lo[1] = (int)(((unsigned)p0[2]) >> 16) | (p0[3] & 0xffff0000);
                lo[2] = (int)(((unsigned)p1[0]) >> 16) | (p1[1] & 0xffff0000);
                lo[3] = (int)(((unsigned)p1[2]) >> 16) | (p1[3] & 0xffff0000);
                b1h[kc][et] = __builtin_bit_cast(half8, hi);
                b1l[kc][et] = __builtin_bit_cast(half8, lo);
            }

        // ================= head =================
#pragma unroll
        for (int et = 0; et < 2; ++et) {
            float l0 = l0p[et];
            l0 += __shfl_xor(l0, 16); l0 += __shfl_xor(l0, 32); l0 += bl0;
            float l1 = l1p[et];
            l1 += __shfl_xor(l1, 16); l1 += __shfl_xor(l1, 32); l1 += bl1;

            float p0 = sigmoid_f(l0 - l1);
            float p1 = sigmoid_f(l1 - l0);
            float y0 = sqrtf(p0), y1 = sqrtf(p1);
            float ph0 = PI_F * l0 * rcp_fast(1.0f + fabsf(l0));
            float ph1 = PI_F * l1 * rcp_fast(1.0f + fabsf(l1));

            int bit = (int)((bm[et] >> step) & 1ull);
            bool is_even = (step & 1) == 0;
            float num   = is_even ? nu[et] : nd[et];
            float lower = -16.0f + (float)(step >> 1);
            float occ   = (num < 16.0f) ? 1.0f : 0.0f;
            float unocc = (num > lower) ? 1.0f : 0.0f;
            if (step >= 16) {
                float m0 = y0 * unocc, m1 = y1 * occ;
                float nrm = fmaxf(sqrtf(m0 * m0 + m1 * m1), 1e-12f);
                float rn  = rcp_fast(nrm);
                y0 = m0 * rn; y1 = m1 * rn;
            }
            if (is_even) nu[et] += (float)bit; else nd[et] += (float)bit;
            amp[et] *= bit ? y1 : y0;
            phs[et] += bit ? ph1 : ph0;
        }
    }

    if (q == 0) {
#pragma unroll
        for (int et = 0; et < 2; ++et) {
            int e = eBase + et * 16 + l4;
            if (e < nbatch) {
                float s, c;
                sincosf(phs[et], &s, &c);
                out[e]          = amp[et] * c;
                out[nbatch + e] = amp[et] * s;
            }
        }
    }
}

extern "C" void kernel_launch(void* const* d_in, const int* in_sizes, int n_in,
                              void* d_out, int out_size, void* d_ws, size_t ws_size,
                              hipStream_t stream) {
    const int*   x     = (const int*)  d_in[0];
    const float* w_ih0 = (const float*)d_in[1];
    const float* w_hh0 = (const float*)d_in[2];
    const float* w_ih1 = (const float*)d_in[3];
    const float* w_hh1 = (const float*)d_in[4];
    const float* w_lin = (const float*)d_in[5];
    const float* b_lin = (const float*)d_in[6];
    float* out = (float*)d_out;
    _Float16* wsp = (_Float16*)d_ws;

    const int nbatch = in_sizes[0] / 64;

    prep_kernel<<<384, 256, 0, stream>>>(w_hh0, w_ih1, w_hh1, wsp);

    const int blocks = (nbatch + 127) / 128;
    rnn_wf_mfma<<<blocks, 256, 0, stream>>>(x, w_ih0, w_lin, b_lin, wsp, out, nbatch);
}

// Round 4
// 14976.311 us; speedup vs baseline: 17.3581x; 1.0800x over previous
//
#include <hip/hip_runtime.h>
#include <math.h>

#define NSTEP 64
#define PI_F 3.14159265358979323846f

typedef _Float16 half8 __attribute__((ext_vector_type(8)));
typedef float f32x4 __attribute__((ext_vector_type(4)));
typedef int int4v __attribute__((ext_vector_type(4)));

#define MFMA(a, b, c) __builtin_amdgcn_mfma_f32_16x16x32_f16(a, b, c, 0, 0, 0)

// ws layout in halfs: [whh0_hi 49152][whh0_lo 49152][wcat_hi 98304][wcat_lo 98304]
#define OFF_HH0_LO 49152
#define OFF_CAT_HI 98304
#define OFF_CAT_LO 196608

__device__ __forceinline__ float rcp_fast(float x) { return __builtin_amdgcn_rcpf(x); }
__device__ __forceinline__ float sigmoid_f(float x) {
    float e = __expf(-x);
    return rcp_fast(1.0f + e);
}
__device__ __forceinline__ float tanh_f(float x) {
    float ax = fabsf(x);
    float e  = __expf(-2.0f * ax);
    float t  = (1.0f - e) * rcp_fast(1.0f + e);
    return x >= 0.0f ? t : -t;
}
__device__ __forceinline__ float f16lo(int v) {
    return (float)__builtin_bit_cast(_Float16, (unsigned short)(v & 0xffff));
}
__device__ __forceinline__ float f16hi(int v) {
    return (float)__builtin_bit_cast(_Float16, (unsigned short)((unsigned)v >> 16));
}
__device__ __forceinline__ int pack_split(float f) {
    _Float16 hi = (_Float16)f;
    _Float16 lo = (_Float16)(f - (float)hi);
    return (int)__builtin_bit_cast(unsigned short, hi) |
           ((int)__builtin_bit_cast(unsigned short, lo) << 16);
}

// Prep: split fp32 weights into f16 hi/lo planes; concat [w_ih1|w_hh1] along K.
__global__ void prep_kernel(const float* __restrict__ whh0,
                            const float* __restrict__ wih1,
                            const float* __restrict__ whh1,
                            _Float16* __restrict__ wsp) {
    int i = blockIdx.x * 256 + threadIdx.x;
    if (i < 49152) {
        float v = whh0[i];
        _Float16 h = (_Float16)v;
        wsp[i] = h;
        wsp[OFF_HH0_LO + i] = (_Float16)(v - (float)h);
    }
    if (i < 98304) {
        int n = i >> 8, k = i & 255;
        float v = (k < 128) ? wih1[(n << 7) + k] : whh1[(n << 7) + k - 128];
        _Float16 h = (_Float16)v;
        wsp[OFF_CAT_HI + i] = h;
        wsp[OFF_CAT_LO + i] = (_Float16)(v - (float)h);
    }
}

__global__ void __launch_bounds__(256, 1) rnn_wf_mfma(
    const int*   __restrict__ x,
    const float* __restrict__ w_ih0,
    const float* __restrict__ w_lin,
    const float* __restrict__ b_lin,
    const _Float16* __restrict__ wsp,
    float*       __restrict__ out,
    int nbatch)
{
    __shared__ float gi0T[2][3][128];     // [bit][gate][d]
    __shared__ int   hscr[4][32 * 132];   // per-wave packed (hi|lo16) h scratch

    const int lane = threadIdx.x & 63;
    const int wv   = threadIdx.x >> 6;
    const int l4   = lane & 15;
    const int q    = lane >> 4;
    const int eBase = blockIdx.x * 128 + wv * 32;

    // stage gi0T: gi0T[b][g][d] = w_ih0[(g*128+d)*2 + b]
    for (int idx = threadIdx.x; idx < 768; idx += 256) {
        int b = idx / 384, rem = idx - b * 384;
        ((float*)gi0T)[b * 384 + rem] = w_ih0[rem * 2 + b];
    }
    __syncthreads();

    // ---- per-element bit masks (2 elements per lane) ----
    unsigned long long bm[2];
#pragma unroll
    for (int et = 0; et < 2; ++et) {
        int e = eBase + et * 16 + l4;
        if (e >= nbatch) e = nbatch - 1;
        const int* xr = x + (size_t)e * 64 + q * 16;
        unsigned long long m = 0ull;
#pragma unroll
        for (int i = 0; i < 16; ++i)
            m |= ((unsigned long long)((unsigned)(xr[i] + 1) >> 1)) << (q * 16 + i);
        m |= __shfl_xor(m, 16);
        m |= __shfl_xor(m, 32);
        bm[et] = m;
    }

    const _Float16* Whh0_hi = wsp;
    const _Float16* Whh0_lo = wsp + OFF_HH0_LO;
    const _Float16* Wcat_hi = wsp + OFF_CAT_HI;
    const _Float16* Wcat_lo = wsp + OFF_CAT_LO;
    const float bl0 = b_lin[0], bl1 = b_lin[1];

    // h state as B-operand fragments (hi/lo f16), [kchunk][etile]
    // b?h[kc][et][j] = h[e = eBase+16*et+l4][dim = 32*kc + 8*q + j]
    half8 b0h[4][2], b0l[4][2], b1h[4][2], b1l[4][2];
    const half8 hz = {0, 0, 0, 0, 0, 0, 0, 0};
#pragma unroll
    for (int kc = 0; kc < 4; ++kc)
#pragma unroll
        for (int et = 0; et < 2; ++et) {
            b0h[kc][et] = hz; b0l[kc][et] = hz;
            b1h[kc][et] = hz; b1l[kc][et] = hz;
        }

    float amp[2] = {1.0f, 1.0f}, phs[2] = {0.0f, 0.0f};
    float nu[2] = {0.0f, 0.0f}, nd[2] = {0.0f, 0.0f};

    for (int step = 0; step < NSTEP; ++step) {
        __syncthreads();  // phase-lock waves for L1 weight reuse

        // ================= Layer 0: G^T = W_hh0 * h0^T =================
#pragma unroll
        for (int c = 0; c < 8; ++c) {
            f32x4 aR[2], aZ[2], aN[2];
#pragma unroll
            for (int et = 0; et < 2; ++et) {
                aR[et] = (f32x4){0, 0, 0, 0};
                aZ[et] = (f32x4){0, 0, 0, 0};
                aN[et] = (f32x4){0, 0, 0, 0};
            }
#pragma unroll
            for (int kc = 0; kc < 4; ++kc) {
                int off = (16 * c + l4) * 128 + 32 * kc + 8 * q;
                half8 ahR = *(const half8*)(Whh0_hi + off);
                half8 alR = *(const half8*)(Whh0_lo + off);
                half8 ahZ = *(const half8*)(Whh0_hi + off + 128 * 128);
                half8 alZ = *(const half8*)(Whh0_lo + off + 128 * 128);
                half8 ahN = *(const half8*)(Whh0_hi + off + 256 * 128);
                half8 alN = *(const half8*)(Whh0_lo + off + 256 * 128);
#pragma unroll
                for (int et = 0; et < 2; ++et) {
                    half8 bh = b0h[kc][et], bl = b0l[kc][et];
                    aR[et] = MFMA(ahR, bh, aR[et]);
                    aZ[et] = MFMA(ahZ, bh, aZ[et]);
                    aN[et] = MFMA(ahN, bh, aN[et]);
                    aR[et] = MFMA(ahR, bl, aR[et]);
                    aZ[et] = MFMA(ahZ, bl, aZ[et]);
                    aN[et] = MFMA(ahN, bl, aN[et]);
                    aR[et] = MFMA(alR, bh, aR[et]);
                    aZ[et] = MFMA(alZ, bh, aZ[et]);
                    aN[et] = MFMA(alN, bh, aN[et]);
                }
            }
            // ---- epilogue: rows d = 16c + 4q + r, element e = eBase+16et+l4 ----
#pragma unroll
            for (int et = 0; et < 2; ++et) {
                f32x4 giR = {0, 0, 0, 0}, giZ = {0, 0, 0, 0}, giN = {0, 0, 0, 0};
                if (step > 0) {
                    int pb = (int)((bm[et] >> (step - 1)) & 1ull);
                    const float* gp = &gi0T[pb][0][0];
                    int d0 = 16 * c + 4 * q;
                    giR = *(const f32x4*)(gp + d0);
                    giZ = *(const f32x4*)(gp + 128 + d0);
                    giN = *(const f32x4*)(gp + 256 + d0);
                }
                // h0_prev[d][e]: dim d lives in frag kc=c>>1 on lane (q'=2(c&1)+(q>>1), l4=e),
                // register j = 4*(q&1)+r. Shuffle whole frag, select locally.
                int4v Hh = __builtin_bit_cast(int4v, b0h[c >> 1][et]);
                int4v Hl = __builtin_bit_cast(int4v, b0l[c >> 1][et]);
                int src = (((2 * c + (q >> 1)) & 3) << 4) | l4;
                int h0s = __shfl(Hh[0], src), h1s = __shfl(Hh[1], src);
                int h2s = __shfl(Hh[2], src), h3s = __shfl(Hh[3], src);
                int g0s = __shfl(Hl[0], src), g1s = __shfl(Hl[1], src);
                int g2s = __shfl(Hl[2], src), g3s = __shfl(Hl[3], src);
                int qodd = q & 1;
                int ah0 = qodd ? h2s : h0s;
                int ah1 = qodd ? h3s : h1s;
                int al0 = qodd ? g2s : g0s;
                int al1 = qodd ? g3s : g1s;
                float hp[4];
                hp[0] = f16lo(ah0) + f16lo(al0);
                hp[1] = f16hi(ah0) + f16hi(al0);
                hp[2] = f16lo(ah1) + f16lo(al1);
                hp[3] = f16hi(ah1) + f16hi(al1);

                int4v pk;
#pragma unroll
                for (int r = 0; r < 4; ++r) {
                    float rr = sigmoid_f(giR[r] + aR[et][r]);
                    float zz = sigmoid_f(giZ[r] + aZ[et][r]);
                    float nn = tanh_f(giN[r] + rr * aN[et][r]);
                    float hn = (1.0f - zz) * nn + zz * hp[r];
                    pk[r] = pack_split(hn);
                }
                *(int4v*)&hscr[wv][(et * 16 + l4) * 132 + 16 * c + 4 * q] = pk;
            }
        }
        // rebuild h0 B-frags from scratch
#pragma unroll
        for (int kc = 0; kc < 4; ++kc)
#pragma unroll
            for (int et = 0; et < 2; ++et) {
                const int4v* p = (const int4v*)&hscr[wv][(et * 16 + l4) * 132 + 32 * kc + 8 * q];
                int4v p0 = p[0], p1 = p[1];
                int4v hi, lo;
                hi[0] = (p0[0] & 0xffff) | (p0[1] << 16);
                hi[1] = (p0[2] & 0xffff) | (p0[3] << 16);
                hi[2] = (p1[0] & 0xffff) | (p1[1] << 16);
                hi[3] = (p1[2] & 0xffff) | (p1[3] << 16);
                lo[0] = (int)(((unsigned)p0[0]) >> 16) | (p0[1] & 0xffff0000);
                lo[1] = (int)(((unsigned)p0[2]) >> 16) | (p0[3] & 0xffff0000);
                lo[2] = (int)(((unsigned)p1[0]) >> 16) | (p1[1] & 0xffff0000);
                lo[3] = (int)(((unsigned)p1[2]) >> 16) | (p1[3] & 0xffff0000);
                b0h[kc][et] = __builtin_bit_cast(half8, hi);
                b0l[kc][et] = __builtin_bit_cast(half8, lo);
            }

        __syncthreads();

        // ===== Layer 1: G^T = [Wih1|Whh1] * [h0;h1]^T, N-gate split =====
        float l0p[2] = {0.0f, 0.0f}, l1p[2] = {0.0f, 0.0f};
#pragma unroll
        for (int c = 0; c < 8; ++c) {
            f32x4 aR[2], aZ[2], aNi[2], aNh[2];
#pragma unroll
            for (int et = 0; et < 2; ++et) {
                aR[et]  = (f32x4){0, 0, 0, 0};
                aZ[et]  = (f32x4){0, 0, 0, 0};
                aNi[et] = (f32x4){0, 0, 0, 0};
                aNh[et] = (f32x4){0, 0, 0, 0};
            }
#pragma unroll
            for (int kc = 0; kc < 8; ++kc) {
                int off = (16 * c + l4) * 256 + 32 * kc + 8 * q;
                half8 ahR = *(const half8*)(Wcat_hi + off);
                half8 alR = *(const half8*)(Wcat_lo + off);
                half8 ahZ = *(const half8*)(Wcat_hi + off + 128 * 256);
                half8 alZ = *(const half8*)(Wcat_lo + off + 128 * 256);
                half8 ahN = *(const half8*)(Wcat_hi + off + 256 * 256);
                half8 alN = *(const half8*)(Wcat_lo + off + 256 * 256);
#pragma unroll
                for (int et = 0; et < 2; ++et) {
                    half8 bh = (kc < 4) ? b0h[kc][et] : b1h[kc - 4][et];
                    half8 bl = (kc < 4) ? b0l[kc][et] : b1l[kc - 4][et];
                    aR[et] = MFMA(ahR, bh, aR[et]);
                    aZ[et] = MFMA(ahZ, bh, aZ[et]);
                    aR[et] = MFMA(ahR, bl, aR[et]);
                    aZ[et] = MFMA(ahZ, bl, aZ[et]);
                    aR[et] = MFMA(alR, bh, aR[et]);
                    aZ[et] = MFMA(alZ, bh, aZ[et]);
                    if (kc < 4) {
                        aNi[et] = MFMA(ahN, bh, aNi[et]);
                        aNi[et] = MFMA(ahN, bl, aNi[et]);
                        aNi[et] = MFMA(alN, bh, aNi[et]);
                    } else {
                        aNh[et] = MFMA(ahN, bh, aNh[et]);
                        aNh[et] = MFMA(ahN, bl, aNh[et]);
                        aNh[et] = MFMA(alN, bh, aNh[et]);
                    }
                }
            }
#pragma unroll
            for (int et = 0; et < 2; ++et) {
                int4v Hh = __builtin_bit_cast(int4v, b1h[c >> 1][et]);
                int4v Hl = __builtin_bit_cast(int4v, b1l[c >> 1][et]);
                int src = (((2 * c + (q >> 1)) & 3) << 4) | l4;
                int h0s = __shfl(Hh[0], src), h1s = __shfl(Hh[1], src);
                int h2s = __shfl(Hh[2], src), h3s = __shfl(Hh[3], src);
                int g0s = __shfl(Hl[0], src), g1s = __shfl(Hl[1], src);
                int g2s = __shfl(Hl[2], src), g3s = __shfl(Hl[3], src);
                int qodd = q & 1;
                int ah0 = qodd ? h2s : h0s;
                int ah1 = qodd ? h3s : h1s;
                int al0 = qodd ? g2s : g0s;
                int al1 = qodd ? g3s : g1s;
                float hp[4];
                hp[0] = f16lo(ah0) + f16lo(al0);
                hp[1] = f16hi(ah0) + f16hi(al0);
                hp[2] = f16lo(ah1) + f16lo(al1);
                hp[3] = f16hi(ah1) + f16hi(al1);

                f32x4 wl0 = *(const f32x4*)(w_lin + 16 * c + 4 * q);
                f32x4 wl1 = *(const f32x4*)(w_lin + 128 + 16 * c + 4 * q);
                int4v pk;
#pragma unroll
                for (int r = 0; r < 4; ++r) {
                    float rr = sigmoid_f(aR[et][r]);
                    float zz = sigmoid_f(aZ[et][r]);
                    float nn = tanh_f(aNi[et][r] + rr * aNh[et][r]);
                    float hn = (1.0f - zz) * nn + zz * hp[r];
                    l0p[et] = fmaf(hn, wl0[r], l0p[et]);
                    l1p[et] = fmaf(hn, wl1[r], l1p[et]);
                    pk[r] = pack_split(hn);
                }
                *(int4v*)&hscr[wv][(et * 16 + l4) * 132 + 16 * c + 4 * q] = pk;
            }
        }
        // rebuild h1 B-frags
#pragma unroll
        for (int kc = 0; kc < 4; ++kc)
#pragma unroll
            for (int et = 0; et < 2; ++et) {
                const int4v* p = (const int4v*)&hscr[wv][(et * 16 + l4) * 132 + 32 * kc + 8 * q];
                int4v p0 = p[0], p1 = p[1];
                int4v hi, lo;
                hi[0] = (p0[0] & 0xffff) | (p0[1] << 16);
                hi[1] = (p0[2] & 0xffff) | (p0[3] << 16);
                hi[2] = (p1[0] & 0xffff) | (p1[1] << 16);
                hi[3] = (p1[2] & 0xffff) | (p1[3] << 16);
                lo[0] = (int)(((unsigned)p0[0]) >> 16) | (p0[1] & 0xffff0000);
                lo[1] = (int)(((unsigned)p0[2]) >> 16) | (p0[3] & 0xffff0000);
                lo[2] = (int)(((unsigned)p1[0]) >> 16) | (p1[1] & 0xffff0000);
                lo[3] = (int)(((unsigned)p1[2]) >> 16) | (p1[3] & 0xffff0000);
                b1h[kc][et] = __builtin_bit_cast(half8, hi);
                b1l[kc][et] = __builtin_bit_cast(half8, lo);
            }

        // ================= head =================
#pragma unroll
        for (int et = 0; et < 2; ++et) {
            float l0 = l0p[et];
            l0 += __shfl_xor(l0, 16); l0 += __shfl_xor(l0, 32); l0 += bl0;
            float l1 = l1p[et];
            l1 += __shfl_xor(l1, 16); l1 += __shfl_xor(l1, 32); l1 += bl1;

            float p0 = sigmoid_f(l0 - l1);
            float p1 = sigmoid_f(l1 - l0);
            float y0 = sqrtf(p0), y1 = sqrtf(p1);
            float ph0 = PI_F * l0 * rcp_fast(1.0f + fabsf(l0));
            float ph1 = PI_F * l1 * rcp_fast(1.0f + fabsf(l1));

            int bit = (int)((bm[et] >> step) & 1ull);
            bool is_even = (step & 1) == 0;
            float num   = is_even ? nu[et] : nd[et];
            float lower = -16.0f + (float)(step >> 1);
            float occ   = (num < 16.0f) ? 1.0f : 0.0f;
            float unocc = (num > lower) ? 1.0f : 0.0f;
            if (step >= 16) {
                float m0 = y0 * unocc, m1 = y1 * occ;
                float nrm = fmaxf(sqrtf(m0 * m0 + m1 * m1), 1e-12f);
                float rn  = rcp_fast(nrm);
                y0 = m0 * rn; y1 = m1 * rn;
            }
            if (is_even) nu[et] += (float)bit; else nd[et] += (float)bit;
            amp[et] *= bit ? y1 : y0;
            phs[et] += bit ? ph1 : ph0;
        }
    }

    if (q == 0) {
#pragma unroll
        for (int et = 0; et < 2; ++et) {
            int e = eBase + et * 16 + l4;
            if (e < nbatch) {
                float s, c;
                sincosf(phs[et], &s, &c);
                out[e]          = amp[et] * c;
                out[nbatch + e] = amp[et] * s;
            }
        }
    }
}

extern "C" void kernel_launch(void* const* d_in, const int* in_sizes, int n_in,
                              void* d_out, int out_size, void* d_ws, size_t ws_size,
                              hipStream_t stream) {
    const int*   x     = (const int*)  d_in[0];
    const float* w_ih0 = (const float*)d_in[1];
    const float* w_hh0 = (const float*)d_in[2];
    const float* w_ih1 = (const float*)d_in[3];
    const float* w_hh1 = (const float*)d_in[4];
    const float* w_lin = (const float*)d_in[5];
    const float* b_lin = (const float*)d_in[6];
    float* out = (float*)d_out;
    _Float16* wsp = (_Float16*)d_ws;

    const int nbatch = in_sizes[0] / 64;

    prep_kernel<<<384, 256, 0, stream>>>(w_hh0, w_ih1, w_hh1, wsp);

    const int blocks = (nbatch + 127) / 128;
    rnn_wf_mfma<<<blocks, 256, 0, stream>>>(x, w_ih0, w_lin, b_lin, wsp, out, nbatch);
}